// Round 1
// baseline (303.323 us; speedup 1.0000x reference)
//
#include <hip/hip_runtime.h>
#include <math.h>

#define NIMG 8
#define NCLS 19
#define IMG_H 512
#define IMG_W 512
#define HW (IMG_H * IMG_W)

// ---------------------------------------------------------------------------
// Pass 1: per-image class histograms (seg + attention-masked) and global
// pos/neg counts for BCE. Shared-memory histograms, one global atomic per bin
// per block.
// ---------------------------------------------------------------------------
__global__ __launch_bounds__(256) void hist_kernel(
    const float* __restrict__ edgein,
    const int* __restrict__ segmask,
    const int* __restrict__ edgemask,
    unsigned* __restrict__ seg_counts,   // [NIMG*NCLS]
    unsigned* __restrict__ att_counts,   // [NIMG*NCLS]
    unsigned* __restrict__ posneg)       // [2]
{
    __shared__ unsigned s_seg[NCLS];
    __shared__ unsigned s_att[NCLS];
    __shared__ unsigned s_pn[2];

    const int n = blockIdx.y;
    const int tid = threadIdx.x;
    if (tid < NCLS) { s_seg[tid] = 0u; s_att[tid] = 0u; }
    if (tid < 2) s_pn[tid] = 0u;
    __syncthreads();

    const size_t base = (size_t)n * HW;
    unsigned pos = 0, neg = 0;
    for (int i = blockIdx.x * blockDim.x + tid; i < HW;
         i += gridDim.x * blockDim.x) {
        const int t = segmask[base + i];
        const float e = edgein[base + i];
        const int te = edgemask[base + i];
        const bool valid = ((unsigned)t < NCLS);
        if (valid) {
            atomicAdd(&s_seg[t], 1u);
            if (e > 0.8f) atomicAdd(&s_att[t], 1u);
        }
        pos += (te == 1);
        neg += (te == 0);
    }
    atomicAdd(&s_pn[0], pos);
    atomicAdd(&s_pn[1], neg);
    __syncthreads();

    if (tid < NCLS) {
        atomicAdd(&seg_counts[n * NCLS + tid], s_seg[tid]);
        atomicAdd(&att_counts[n * NCLS + tid], s_att[tid]);
    }
    if (tid < 2) atomicAdd(&posneg[tid], s_pn[tid]);
}

// ---------------------------------------------------------------------------
// Pass 2: per-(image,class) weights  w = (count>0)*(1 - count/total) + 1
// Tiny: one block.
// ---------------------------------------------------------------------------
__global__ void weights_kernel(
    const unsigned* __restrict__ seg_counts,
    const unsigned* __restrict__ att_counts,
    float* __restrict__ w_seg,
    float* __restrict__ w_att)
{
    const int idx = threadIdx.x;
    if (idx < NIMG * NCLS) {
        const int n = idx / NCLS;
        float tot = 0.f, tota = 0.f;
        for (int j = 0; j < NCLS; j++) {
            tot  += (float)seg_counts[n * NCLS + j];
            tota += (float)att_counts[n * NCLS + j];
        }
        tot  = fmaxf(tot, 1.0f);
        tota = fmaxf(tota, 1.0f);
        const float c  = (float)seg_counts[idx];
        const float ca = (float)att_counts[idx];
        w_seg[idx] = (c  > 0.f ? (1.0f - c  / tot ) : 0.0f) + 1.0f;
        w_att[idx] = (ca > 0.f ? (1.0f - ca / tota) : 0.0f) + 1.0f;
    }
}

__device__ inline float wave_reduce_add(float v) {
    #pragma unroll
    for (int off = 32; off > 0; off >>= 1)
        v += __shfl_down(v, off, 64);
    return v;
}

// ---------------------------------------------------------------------------
// Pass 3: main fused pass. Per pixel: 19-way log-sum-exp over segin (register
// resident), weighted NLL accumulation for seg and att, class-balanced BCE.
// sums layout: [0..7]=wplp_seg  [8..15]=wp_seg  [16..23]=wplp_att
//              [24..31]=wp_att  [32..39]=bce (per-image to spread atomics)
// ---------------------------------------------------------------------------
__global__ __launch_bounds__(256) void main_kernel(
    const float* __restrict__ segin,
    const float* __restrict__ edgein,
    const int* __restrict__ segmask,
    const int* __restrict__ edgemask,
    const float* __restrict__ w_seg,
    const float* __restrict__ w_att,
    const unsigned* __restrict__ posneg,
    float* __restrict__ sums)
{
    const int n = blockIdx.y;
    const int tid = threadIdx.x;

    const float pos_num = (float)posneg[0];
    const float neg_num = (float)posneg[1];
    const float s = fmaxf(pos_num + neg_num, 1.0f);
    const float wpos = neg_num / s;   // weight for target==1
    const float wneg = pos_num / s;   // weight for target==0

    __shared__ float l_wseg[NCLS];
    __shared__ float l_watt[NCLS];
    if (tid < NCLS) {
        l_wseg[tid] = w_seg[n * NCLS + tid];
        l_watt[tid] = w_att[n * NCLS + tid];
    }
    __syncthreads();

    float a_wplp_seg = 0.f, a_wp_seg = 0.f;
    float a_wplp_att = 0.f, a_wp_att = 0.f;
    float a_bce = 0.f;

    const size_t ibase = (size_t)n * HW;
    const float* seg_n = segin + (size_t)n * NCLS * HW;

    for (int i = blockIdx.x * blockDim.x + tid; i < HW;
         i += gridDim.x * blockDim.x) {
        const int t = segmask[ibase + i];
        const bool valid = ((unsigned)t < NCLS);
        const int tc = valid ? t : 0;

        float x[NCLS];
        #pragma unroll
        for (int c = 0; c < NCLS; c++)
            x[c] = seg_n[(size_t)c * HW + i];

        float mx = x[0];
        #pragma unroll
        for (int c = 1; c < NCLS; c++) mx = fmaxf(mx, x[c]);

        float se = 0.f;
        float xt = x[0];
        #pragma unroll
        for (int c = 0; c < NCLS; c++) {
            se += expf(x[c] - mx);
            if (c == tc) xt = x[c];   // select-chain, no dynamic indexing
        }
        const float lse = mx + logf(se);
        const float lpt = xt - lse;

        if (valid) {
            const float w = l_wseg[tc];
            a_wplp_seg += w * lpt;
            a_wp_seg   += w;
        }
        const float e = edgein[ibase + i];
        if (valid && e > 0.8f) {
            const float w = l_watt[tc];
            a_wplp_att += w * lpt;
            a_wp_att   += w;
        }
        const int te = edgemask[ibase + i];
        const float tf = (float)te;
        const float wb = (te == 1) ? wpos : ((te == 0) ? wneg : 0.0f);
        const float bce = fmaxf(e, 0.f) - e * tf + log1pf(expf(-fabsf(e)));
        a_bce += wb * bce;
    }

    // block reduction: wave shuffle -> LDS -> single atomic per block per slot
    __shared__ float red[5][4];
    const int wave = tid >> 6;
    const int lane = tid & 63;
    a_wplp_seg = wave_reduce_add(a_wplp_seg);
    a_wp_seg   = wave_reduce_add(a_wp_seg);
    a_wplp_att = wave_reduce_add(a_wplp_att);
    a_wp_att   = wave_reduce_add(a_wp_att);
    a_bce      = wave_reduce_add(a_bce);
    if (lane == 0) {
        red[0][wave] = a_wplp_seg;
        red[1][wave] = a_wp_seg;
        red[2][wave] = a_wplp_att;
        red[3][wave] = a_wp_att;
        red[4][wave] = a_bce;
    }
    __syncthreads();
    if (tid == 0) {
        #pragma unroll
        for (int k = 0; k < 5; k++) {
            const float v = red[k][0] + red[k][1] + red[k][2] + red[k][3];
            atomicAdd(&sums[k * NIMG + n], v);
        }
    }
}

// ---------------------------------------------------------------------------
// Pass 4: finalize the 4 outputs.
// ---------------------------------------------------------------------------
__global__ void final_kernel(const float* __restrict__ sums,
                             float* __restrict__ out)
{
    if (threadIdx.x == 0) {
        float seg = 0.f, att = 0.f, bce = 0.f;
        for (int n = 0; n < NIMG; n++) {
            seg += -sums[0 * NIMG + n] / fmaxf(sums[1 * NIMG + n], 1e-12f);
            att += -sums[2 * NIMG + n] / fmaxf(sums[3 * NIMG + n], 1e-12f);
            bce += sums[4 * NIMG + n];
        }
        out[0] = seg;
        out[1] = 20.0f * bce / (float)(NIMG * HW);
        out[2] = att;
        out[3] = 0.0f;
    }
}

extern "C" void kernel_launch(void* const* d_in, const int* in_sizes, int n_in,
                              void* d_out, int out_size, void* d_ws, size_t ws_size,
                              hipStream_t stream) {
    const float* segin    = (const float*)d_in[0];
    const float* edgein   = (const float*)d_in[1];
    const int*   segmask  = (const int*)d_in[2];
    const int*   edgemask = (const int*)d_in[3];
    float* out = (float*)d_out;

    // workspace layout
    unsigned* seg_counts = (unsigned*)d_ws;                   // 152
    unsigned* att_counts = seg_counts + NIMG * NCLS;          // 152
    unsigned* posneg     = att_counts + NIMG * NCLS;          // 2
    float*    w_seg      = (float*)(posneg + 2);              // 152
    float*    w_att      = w_seg + NIMG * NCLS;               // 152
    float*    sums       = w_att + NIMG * NCLS;               // 40

    const size_t zbytes =
        (size_t)(2 * NIMG * NCLS + 2) * sizeof(unsigned) +
        (size_t)(2 * NIMG * NCLS + 5 * NIMG) * sizeof(float);
    hipMemsetAsync(d_ws, 0, zbytes, stream);

    hist_kernel<<<dim3(128, NIMG), 256, 0, stream>>>(
        edgein, segmask, edgemask, seg_counts, att_counts, posneg);
    weights_kernel<<<1, 256, 0, stream>>>(seg_counts, att_counts, w_seg, w_att);
    main_kernel<<<dim3(256, NIMG), 256, 0, stream>>>(
        segin, edgein, segmask, edgemask, w_seg, w_att, posneg, sums);
    final_kernel<<<1, 64, 0, stream>>>(sums, out);
}

// Round 2
// 260.922 us; speedup vs baseline: 1.1625x; 1.1625x over previous
//
#include <hip/hip_runtime.h>
#include <math.h>

#define NIMG 8
#define NCLS 19
#define IMG_H 512
#define IMG_W 512
#define HW (IMG_H * IMG_W)
#define NQ (HW / 4)

// ws layout: g_bins[4][NIMG][NCLS] (acc: 0=seg_lpt 1=seg_cnt 2=att_lpt 3=att_cnt)
//            g_sc[NIMG][4]         (0=bce_pos 1=bce_neg 2=pos_cnt 3=neg_cnt)
#define GBINS(acc, n, c) (((acc) * NIMG + (n)) * NCLS + (c))

__device__ inline float wave_reduce_add(float v) {
    #pragma unroll
    for (int off = 32; off > 0; off >>= 1)
        v += __shfl_down(v, off, 64);
    return v;
}

// ---------------------------------------------------------------------------
// Single fused pass. Per quad-pixel: 19-way sum-exp over segin (float4),
// per-(lane,class) LDS accumulation of lpt-sums & counts (seg + att-masked),
// register accumulation of BCE pos/neg partial sums.
// ---------------------------------------------------------------------------
__global__ __launch_bounds__(256) void main_kernel(
    const float* __restrict__ segin,
    const float* __restrict__ edgein,
    const int* __restrict__ segmask,
    const int* __restrict__ edgemask,
    float* __restrict__ g_bins,
    float* __restrict__ g_sc)
{
    // per-lane bins: [acc][lane][class]; stride 19 coprime to 32 banks
    __shared__ float s_bins[4 * 64 * 19];
    __shared__ float s_red[4][4];

    const int n = blockIdx.y;
    const int tid = threadIdx.x;
    const int lane = tid & 63;
    const int wave = tid >> 6;

    for (int i = tid; i < 4 * 64 * 19; i += 256) s_bins[i] = 0.f;
    __syncthreads();

    float* bl_slpt = &s_bins[(0 * 64 + lane) * 19];
    float* bl_scnt = &s_bins[(1 * 64 + lane) * 19];
    float* bl_alpt = &s_bins[(2 * 64 + lane) * 19];
    float* bl_acnt = &s_bins[(3 * 64 + lane) * 19];

    const float4* segq  = (const float4*)(segin  + (size_t)n * NCLS * HW);
    const float4* edgeq = (const float4*)(edgein + (size_t)n * HW);
    const int4*   smq   = (const int4*)(segmask  + (size_t)n * HW);
    const int4*   emq   = (const int4*)(edgemask + (size_t)n * HW);

    float bp = 0.f, bn = 0.f, pc = 0.f, nc = 0.f;

    for (int q = blockIdx.x * blockDim.x + tid; q < NQ;
         q += gridDim.x * blockDim.x) {
        const int4 t4  = smq[q];
        const int4 te4 = emq[q];
        const float4 e4 = edgeq[q];

        const bool v0 = ((unsigned)t4.x < NCLS);
        const bool v1 = ((unsigned)t4.y < NCLS);
        const bool v2 = ((unsigned)t4.z < NCLS);
        const bool v3 = ((unsigned)t4.w < NCLS);
        const int tc0 = v0 ? t4.x : 0;
        const int tc1 = v1 ? t4.y : 0;
        const int tc2 = v2 ? t4.z : 0;
        const int tc3 = v3 ? t4.w : 0;

        float se0 = 0.f, se1 = 0.f, se2 = 0.f, se3 = 0.f;
        float xt0 = 0.f, xt1 = 0.f, xt2 = 0.f, xt3 = 0.f;
        #pragma unroll
        for (int c = 0; c < NCLS; c++) {
            const float4 x = segq[(size_t)c * NQ + q];
            se0 += __expf(x.x);
            se1 += __expf(x.y);
            se2 += __expf(x.z);
            se3 += __expf(x.w);
            xt0 = (c == tc0) ? x.x : xt0;
            xt1 = (c == tc1) ? x.y : xt1;
            xt2 = (c == tc2) ? x.z : xt2;
            xt3 = (c == tc3) ? x.w : xt3;
        }
        const float lp0 = xt0 - __logf(se0);
        const float lp1 = xt1 - __logf(se1);
        const float lp2 = xt2 - __logf(se2);
        const float lp3 = xt3 - __logf(se3);

        if (v0) { atomicAdd(&bl_slpt[tc0], lp0); atomicAdd(&bl_scnt[tc0], 1.f);
                  if (e4.x > 0.8f) { atomicAdd(&bl_alpt[tc0], lp0); atomicAdd(&bl_acnt[tc0], 1.f); } }
        if (v1) { atomicAdd(&bl_slpt[tc1], lp1); atomicAdd(&bl_scnt[tc1], 1.f);
                  if (e4.y > 0.8f) { atomicAdd(&bl_alpt[tc1], lp1); atomicAdd(&bl_acnt[tc1], 1.f); } }
        if (v2) { atomicAdd(&bl_slpt[tc2], lp2); atomicAdd(&bl_scnt[tc2], 1.f);
                  if (e4.z > 0.8f) { atomicAdd(&bl_alpt[tc2], lp2); atomicAdd(&bl_acnt[tc2], 1.f); } }
        if (v3) { atomicAdd(&bl_slpt[tc3], lp3); atomicAdd(&bl_scnt[tc3], 1.f);
                  if (e4.w > 0.8f) { atomicAdd(&bl_alpt[tc3], lp3); atomicAdd(&bl_acnt[tc3], 1.f); } }

        // class-balanced BCE partials (weights applied in finalize)
        const float b0 = fmaxf(e4.x, 0.f) - e4.x * (float)te4.x + __logf(1.f + __expf(-fabsf(e4.x)));
        const float b1 = fmaxf(e4.y, 0.f) - e4.y * (float)te4.y + __logf(1.f + __expf(-fabsf(e4.y)));
        const float b2 = fmaxf(e4.z, 0.f) - e4.z * (float)te4.z + __logf(1.f + __expf(-fabsf(e4.z)));
        const float b3 = fmaxf(e4.w, 0.f) - e4.w * (float)te4.w + __logf(1.f + __expf(-fabsf(e4.w)));
        if (te4.x == 1) { bp += b0; pc += 1.f; } else if (te4.x == 0) { bn += b0; nc += 1.f; }
        if (te4.y == 1) { bp += b1; pc += 1.f; } else if (te4.y == 0) { bn += b1; nc += 1.f; }
        if (te4.z == 1) { bp += b2; pc += 1.f; } else if (te4.z == 0) { bn += b2; nc += 1.f; }
        if (te4.w == 1) { bp += b3; pc += 1.f; } else if (te4.w == 0) { bn += b3; nc += 1.f; }
    }

    // ---- BCE scalar block-reduction ----
    bp = wave_reduce_add(bp);
    bn = wave_reduce_add(bn);
    pc = wave_reduce_add(pc);
    nc = wave_reduce_add(nc);
    if (lane == 0) { s_red[0][wave] = bp; s_red[1][wave] = bn;
                     s_red[2][wave] = pc; s_red[3][wave] = nc; }
    __syncthreads();
    if (tid == 0) {
        #pragma unroll
        for (int k = 0; k < 4; k++)
            atomicAdd(&g_sc[n * 4 + k],
                      s_red[k][0] + s_red[k][1] + s_red[k][2] + s_red[k][3]);
    }

    // ---- bin reduction over 64 lane-replicas: 76 outputs per block ----
    if (tid < 4 * NCLS) {
        const int acc = tid / NCLS;
        const int c = tid - acc * NCLS;
        float s = 0.f;
        #pragma unroll 8
        for (int l = 0; l < 64; l++)
            s += s_bins[(acc * 64 + l) * 19 + c];
        atomicAdd(&g_bins[GBINS(acc, n, c)], s);
    }
}

// ---------------------------------------------------------------------------
// Finalize: weights from counts, weighted combines, 4 outputs.
// ---------------------------------------------------------------------------
__global__ void final_kernel(const float* __restrict__ g_bins,
                             const float* __restrict__ g_sc,
                             float* __restrict__ out)
{
    __shared__ float s_seg[NIMG];
    __shared__ float s_att[NIMG];
    const int t = threadIdx.x;
    if (t < NIMG) {
        const int n = t;
        float tot = 0.f, tota = 0.f;
        for (int c = 0; c < NCLS; c++) {
            tot  += g_bins[GBINS(1, n, c)];
            tota += g_bins[GBINS(3, n, c)];
        }
        tot  = fmaxf(tot, 1.0f);
        tota = fmaxf(tota, 1.0f);
        float wp = 0.f, wplp = 0.f, wpa = 0.f, wplpa = 0.f;
        for (int c = 0; c < NCLS; c++) {
            const float cs = g_bins[GBINS(1, n, c)];
            const float ca = g_bins[GBINS(3, n, c)];
            const float w  = (cs > 0.f) ? (2.0f - cs / tot ) : 1.0f;
            const float wa = (ca > 0.f) ? (2.0f - ca / tota) : 1.0f;
            wp    += w * cs;
            wplp  += w * g_bins[GBINS(0, n, c)];
            wpa   += wa * ca;
            wplpa += wa * g_bins[GBINS(2, n, c)];
        }
        s_seg[n] = -wplp  / fmaxf(wp,  1e-12f);
        s_att[n] = -wplpa / fmaxf(wpa, 1e-12f);
    }
    __syncthreads();
    if (t == 0) {
        float seg = 0.f, att = 0.f, bpt = 0.f, bnt = 0.f, pct = 0.f, nct = 0.f;
        for (int n = 0; n < NIMG; n++) {
            seg += s_seg[n];
            att += s_att[n];
            bpt += g_sc[n * 4 + 0];
            bnt += g_sc[n * 4 + 1];
            pct += g_sc[n * 4 + 2];
            nct += g_sc[n * 4 + 3];
        }
        const float s = fmaxf(pct + nct, 1.0f);
        const float bce = (nct / s) * bpt + (pct / s) * bnt;
        out[0] = seg;
        out[1] = 20.0f * bce / (float)(NIMG * HW);
        out[2] = att;
        out[3] = 0.0f;
    }
}

extern "C" void kernel_launch(void* const* d_in, const int* in_sizes, int n_in,
                              void* d_out, int out_size, void* d_ws, size_t ws_size,
                              hipStream_t stream) {
    const float* segin    = (const float*)d_in[0];
    const float* edgein   = (const float*)d_in[1];
    const int*   segmask  = (const int*)d_in[2];
    const int*   edgemask = (const int*)d_in[3];
    float* out = (float*)d_out;

    float* g_bins = (float*)d_ws;                    // 4*8*19 = 608 floats
    float* g_sc   = g_bins + 4 * NIMG * NCLS;        // 8*4 = 32 floats

    hipMemsetAsync(d_ws, 0, (4 * NIMG * NCLS + 4 * NIMG) * sizeof(float), stream);

    main_kernel<<<dim3(128, NIMG), 256, 0, stream>>>(
        segin, edgein, segmask, edgemask, g_bins, g_sc);
    final_kernel<<<1, 64, 0, stream>>>(g_bins, g_sc, out);
}